// Round 9
// baseline (158.573 us; speedup 1.0000x reference)
//
#include <hip/hip_runtime.h>
#include <math.h>

#define D 768
#define DOUT 384
#define LSEQ 512
#define BATCH 4
#define KTOP 51
#define EPS 1e-5f

typedef unsigned short ushort_t;
typedef __bf16 bf16x8 __attribute__((ext_vector_type(8)));
typedef float f32x4 __attribute__((ext_vector_type(4)));
typedef float f32x2 __attribute__((ext_vector_type(2)));

// global->LDS direct DMA, 16B per lane. LDS dest is wave-uniform base + lane*16.
#define GLOAD16(gp, lp)                                                        \
    __builtin_amdgcn_global_load_lds(                                          \
        (const __attribute__((address_space(1))) unsigned int*)(gp),           \
        (__attribute__((address_space(3))) unsigned int*)(lp), 16, 0, 0)

// fp32 -> bf16 round-to-nearest-even (inputs are finite; NaN path not needed)
__device__ __forceinline__ ushort_t f2bf(float f) {
    unsigned int u = __builtin_bit_cast(unsigned int, f);
    u = (u + 0x7FFFu + ((u >> 16) & 1u)) >> 16;
    return (ushort_t)u;
}

__device__ __forceinline__ float bf2f(ushort_t u) {
    unsigned int v = ((unsigned int)u) << 16;
    return __builtin_bit_cast(float, v);
}

// ---------------------------------------------------------------------------
// Prep: blocks [0,1536) convert hidden fp32->bf16; [1536,2688) do the two
// 768x768 W transposes; 2688 zeroes pooled/z/cnt; [2689,4737) run per-row
// top-51 (depends only on `attention` input -> overlaps with the rest).
// ---------------------------------------------------------------------------
__global__ __launch_bounds__(256) void prep_kernel(const float* __restrict__ hidden,
                                                   ushort_t* __restrict__ Ah,
                                                   const float* __restrict__ W0,
                                                   const float* __restrict__ W1,
                                                   ushort_t* __restrict__ WT0,
                                                   ushort_t* __restrict__ WT1,
                                                   float* __restrict__ pooled,
                                                   float* __restrict__ z,
                                                   int* __restrict__ cnt,
                                                   const float* __restrict__ attn,
                                                   int* __restrict__ kidg,
                                                   float* __restrict__ kvvg) {
    __shared__ float tile[32][33];
    __shared__ float vals[LSEQ];
    __shared__ float cval[320];
    __shared__ int   cidx[320];
    __shared__ int   nhi, outSlot;
    __shared__ int   kid[KTOP];
    __shared__ float kvv[KTOP];

    const int bid = blockIdx.x;
    const int tid = threadIdx.x;
    if (bid < 1536) {
        const int i = (bid * 256 + tid) * 4;
        const float4 v = *(const float4*)(hidden + i);
        ushort4 o;
        o.x = f2bf(v.x); o.y = f2bf(v.y); o.z = f2bf(v.z); o.w = f2bf(v.w);
        *(ushort4*)(Ah + i) = o;
    } else if (bid < 2688) {
        const int t = bid - 1536;
        const int zz = t / 576;
        const int rem = t - zz * 576;
        const int by = rem / 24, bx = rem - by * 24;
        const float* W = zz ? W1 : W0;
        ushort_t* WT = zz ? WT1 : WT0;
        const int kbase = by * 32;
        const int nbase = bx * 32;
        const int r = tid >> 3, c4 = (tid & 7) * 4;

        const float4 v = *(const float4*)(W + (size_t)(kbase + r) * D + nbase + c4);
        tile[r][c4 + 0] = v.x; tile[r][c4 + 1] = v.y;
        tile[r][c4 + 2] = v.z; tile[r][c4 + 3] = v.w;
        __syncthreads();
        ushort4 o;
        o.x = f2bf(tile[c4 + 0][r]); o.y = f2bf(tile[c4 + 1][r]);
        o.z = f2bf(tile[c4 + 2][r]); o.w = f2bf(tile[c4 + 3][r]);
        *(ushort4*)(WT + (size_t)(nbase + r) * D + kbase + c4) = o;
    } else if (bid == 2688) {
        for (int i = tid; i < BATCH * D; i += 256) pooled[i] = 0.f;
        for (int i = tid; i < BATCH * DOUT; i += 256) z[i] = 0.f;
        if (tid < BATCH) cnt[tid] = 0;
    } else {
        // -------- per-row top-51 --------
        const int row = bid - 2689;
        const int lane = tid & 63;
        if (tid == 0) { nhi = 0; outSlot = 0; }

        const float* a = attn + (size_t)row * LSEQ;
        const float v0 = a[tid];
        const float v1 = a[tid + 256];
        vals[tid] = v0;
        vals[tid + 256] = v1;
        __syncthreads();

        // ballot compaction: one LDS atomic per wave (slot order irrelevant —
        // rank below is computed over the candidate SET)
        {
            const unsigned long long m0 = __ballot(v0 > 0.75f);
            const unsigned long long m1 = __ballot(v1 > 0.75f);
            const int c0 = __popcll(m0);
            const int c1 = __popcll(m1);
            int base = 0;
            if (lane == 0) base = atomicAdd(&nhi, c0 + c1);
            base = __shfl(base, 0);
            const unsigned long long below = (1ull << lane) - 1ull;
            if (v0 > 0.75f) {
                const int s = base + __popcll(m0 & below);
                if (s < 320) { cval[s] = v0; cidx[s] = tid; }
            }
            if (v1 > 0.75f) {
                const int s = base + c0 + __popcll(m1 & below);
                if (s < 320) { cval[s] = v1; cidx[s] = tid + 256; }
            }
        }
        __syncthreads();

        const int n = nhi;
        if (n >= KTOP && n <= 320) {
            // fast path: rank within survivor set == global rank for survivors
            if (tid < n) {
                const float v = cval[tid];
                const int e = cidx[tid];
                int r = 0;
                int j = 0;
                const int n4 = n & ~3;
                for (; j < n4; j += 4) {
                    const float4 u4 = *(const float4*)&cval[j];
                    const int4 e4 = *(const int4*)&cidx[j];
                    r += (u4.x > v) || (u4.x == v && e4.x < e);
                    r += (u4.y > v) || (u4.y == v && e4.y < e);
                    r += (u4.z > v) || (u4.z == v && e4.z < e);
                    r += (u4.w > v) || (u4.w == v && e4.w < e);
                }
                for (; j < n; ++j) {
                    const float u = cval[j];
                    r += (u > v) || (u == v && cidx[j] < e);
                }
                const bool keep = (r < KTOP);
                const unsigned long long mk = __ballot(keep);
                const int cntk = __popcll(mk);
                if (cntk > 0) {
                    const int leader = __ffsll((unsigned long long)mk) - 1;
                    int base = 0;
                    if (lane == leader) base = atomicAdd(&outSlot, cntk);
                    base = __shfl(base, leader);
                    if (keep) {
                        const int s = base + __popcll(mk & ((1ull << lane) - 1ull));
                        kid[s] = e; kvv[s] = v;
                    }
                }
            }
        } else {
            // exact fallback for arbitrary inputs (rare; serial atomics fine)
#pragma unroll
            for (int e0 = 0; e0 < 2; ++e0) {
                const int e = tid + e0 * 256;
                const float v = vals[e];
                int r = 0;
                for (int j = 0; j < LSEQ; ++j) {
                    const float u = vals[j];
                    r += (u > v) || (u == v && j < e);
                }
                if (r < KTOP) {
                    const int s = atomicAdd(&outSlot, 1);
                    kid[s] = e; kvv[s] = v;
                }
            }
        }
        __syncthreads();
        if (tid < KTOP) {
            kidg[(size_t)row * 64 + tid] = kid[tid];
            kvvg[(size_t)row * 64 + tid] = kvv[tid];
        }
    }
}

// ---------------------------------------------------------------------------
// Feature GEMM (bf16 MFMA): A(2048x768) @ W(768x768) + bias.
// 64x64 tiles, BK=64, chunk-XOR swizzle on both sides. Flattened 768-block
// grid with XCD-aware bijective swizzle; 768 blocks = exactly 3/CU.
// zz==0: W_src -> fsrc_bf (bf16). zz==1: W_dst -> feat_dst (fp32).
// ---------------------------------------------------------------------------
__global__ __launch_bounds__(256) void feat_gemm_kernel(const ushort_t* __restrict__ Ah,
                                                        const ushort_t* __restrict__ WT0,
                                                        const float* __restrict__ b0,
                                                        ushort_t* __restrict__ Csrc_bf,
                                                        const ushort_t* __restrict__ WT1,
                                                        const float* __restrict__ b1,
                                                        float* __restrict__ Cdst) {
    const int bid = blockIdx.x;
    const int wid = (bid & 7) * 96 + (bid >> 3);   // bijective XCD swizzle
    const int zz = wid / 384;
    const int rem = wid - zz * 384;
    const int tileY = rem / 12;          // 0..31 (row-block over M)
    const int tileX = rem - tileY * 12;  // 0..11 (col-block over D)

    const ushort_t* WT = zz ? WT1 : WT0;
    const float* bias = zz ? b1 : b0;

    __shared__ ushort_t As[64 * 64];   // 8 KB
    __shared__ ushort_t Bs[64 * 64];   // 8 KB

    const int tid = threadIdx.x;
    const int lane = tid & 63;
    const int wave = tid >> 6;
    const int quad = lane >> 4;
    const int m15 = lane & 15;
    const int qRow = (wave & 1) * 32;
    const int qCol = (wave >> 1) * 32;

    const int rowBase = tileY * 64;
    const int colBase = tileX * 64;

    const int e0 = tid * 8;          // 2048 bf16 per pass
    const int r0 = e0 >> 6;          // 0..31
    const int c0 = e0 & 63;
    const int cc = c0 >> 3;          // 16B chunk 0..7
    const int csw = (cc ^ (r0 & 7)) << 3;   // swizzled source column
    const ushort_t* Abase = Ah + (size_t)rowBase * D;
    const ushort_t* Bbase = WT + (size_t)colBase * D;

    f32x4 acc[2][2] = {};

    for (int kk = 0; kk < D; kk += 64) {
        __syncthreads();
        GLOAD16(Abase + (size_t)r0 * D + kk + csw, &As[e0]);
        GLOAD16(Abase + (size_t)(r0 + 32) * D + kk + csw, &As[e0 + 2048]);
        GLOAD16(Bbase + (size_t)r0 * D + kk + csw, &Bs[e0]);
        GLOAD16(Bbase + (size_t)(r0 + 32) * D + kk + csw, &Bs[e0 + 2048]);
        __syncthreads();

        bf16x8 a[2][2], b[2][2];
#pragma unroll
        for (int i = 0; i < 2; ++i) {
            const int row = qRow + i * 16 + m15;
            const int sw = row & 7;
#pragma unroll
            for (int ks = 0; ks < 2; ++ks)
                a[i][ks] = *(const bf16x8*)&As[row * 64 + ((((ks << 2) + quad) ^ sw) << 3)];
        }
#pragma unroll
        for (int j = 0; j < 2; ++j) {
            const int row = qCol + j * 16 + m15;
            const int sw = row & 7;
#pragma unroll
            for (int ks = 0; ks < 2; ++ks)
                b[j][ks] = *(const bf16x8*)&Bs[row * 64 + ((((ks << 2) + quad) ^ sw) << 3)];
        }
#pragma unroll
        for (int ks = 0; ks < 2; ++ks)
#pragma unroll
            for (int i = 0; i < 2; ++i)
#pragma unroll
                for (int j = 0; j < 2; ++j)
                    acc[i][j] = __builtin_amdgcn_mfma_f32_16x16x32_bf16(a[i][ks], b[j][ks], acc[i][j], 0, 0, 0);
    }

    // C/D layout: col=lane&15, row=quad*4+reg
    if (zz == 0) {
#pragma unroll
        for (int j = 0; j < 2; ++j) {
            const int col = colBase + qCol + j * 16 + m15;
            const float bv = bias[col];
#pragma unroll
            for (int i = 0; i < 2; ++i) {
                ushort_t* Cp = Csrc_bf + (size_t)(rowBase + qRow + i * 16 + quad * 4) * D + col;
#pragma unroll
                for (int r = 0; r < 4; ++r)
                    Cp[(size_t)r * D] = f2bf(acc[i][j][r] + bv);
            }
        }
    } else {
#pragma unroll
        for (int j = 0; j < 2; ++j) {
            const int col = colBase + qCol + j * 16 + m15;
            const float bv = bias[col];
#pragma unroll
            for (int i = 0; i < 2; ++i) {
                float* Cp = Cdst + (size_t)(rowBase + qRow + i * 16 + quad * 4) * D + col;
#pragma unroll
                for (int r = 0; r < 4; ++r)
                    Cp[(size_t)r * D] = acc[i][j][r] + bv;
            }
        }
    }
}

// ---------------------------------------------------------------------------
// Fused score + gather, 8-WAVE edition (512 threads/row): halves the serial
// per-wave chain (7 iterations of score->reduce->exp->accum instead of 13).
// topk precomputed in prep. Pipelined gather (packed-f32), 8-way flash merge
// in LDS (~25 KB), residual + leaky + h(bf16) store + gate dot.
// ---------------------------------------------------------------------------
__global__ __launch_bounds__(512) void scoregath_kernel(const int* __restrict__ kidg,
                                                        const float* __restrict__ kvvg,
                                                        const ushort_t* __restrict__ fsrc_bf,
                                                        const float* __restrict__ feat_dst,
                                                        const float* __restrict__ attn_vec,
                                                        const float* __restrict__ gat_bias,
                                                        const float* __restrict__ hidden,
                                                        const float* __restrict__ gate_W,
                                                        const float* __restrict__ gate_b,
                                                        ushort_t* __restrict__ h,
                                                        float* __restrict__ gate) {
    const int bid = blockIdx.x;
    const int row = (bid & 7) * 256 + (bid >> 3);   // bijective XCD swizzle
    const int b = row >> 9;
    const int tid = threadIdx.x;
    const int lane = tid & 63;
    const int wave = tid >> 6;      // 0..7

    __shared__ int   kid[KTOP];
    __shared__ float kvv[KTOP];
    __shared__ float wm[8], wl[8];
    __shared__ float hpart[8][D];   // 24 KB
    __shared__ float gred[8];

    if (tid < KTOP) {
        kid[tid] = kidg[(size_t)row * 64 + tid];
        kvv[tid] = kvvg[(size_t)row * 64 + tid];
    }

    // balanced per-lane slice: 12 dims = [lane*8, +8) + [512+lane*4, +4),
    // held as 6 packed f32x2 (v_pk_* on CDNA4)
    const int d0 = lane * 8;
    const int d1 = 512 + lane * 4;
    const float* fdp = feat_dst + (size_t)row * D;
    f32x2 fdr[6], avr[6];
    {
        const float4 f0 = *(const float4*)(fdp + d0);
        const float4 f1 = *(const float4*)(fdp + d0 + 4);
        const float4 f2 = *(const float4*)(fdp + d1);
        const float4 a0 = *(const float4*)(attn_vec + d0);
        const float4 a1 = *(const float4*)(attn_vec + d0 + 4);
        const float4 a2 = *(const float4*)(attn_vec + d1);
        fdr[0] = f32x2{f0.x, f0.y}; fdr[1] = f32x2{f0.z, f0.w};
        fdr[2] = f32x2{f1.x, f1.y}; fdr[3] = f32x2{f1.z, f1.w};
        fdr[4] = f32x2{f2.x, f2.y}; fdr[5] = f32x2{f2.z, f2.w};
        avr[0] = f32x2{a0.x, a0.y}; avr[1] = f32x2{a0.z, a0.w};
        avr[2] = f32x2{a1.x, a1.y}; avr[3] = f32x2{a1.z, a1.w};
        avr[4] = f32x2{a2.x, a2.y}; avr[5] = f32x2{a2.z, a2.w};
    }
    __syncthreads();   // kid/kvv staged

    // single pass: score + online accumulate, wave w owns k = w, w+8, ...
    // software pipeline: preload g[k+8] before processing g[k].
    const ushort_t* fb = fsrc_bf + ((size_t)(b << 9)) * D;
    float m_run = -3.0e38f, l_run = 0.f;
    f32x2 acc[6] = {};

    const ushort_t* gp0 = fb + (size_t)kid[wave] * D;
    bf16x8 cg0 = *(const bf16x8*)(gp0 + d0);
    ushort4 cg1 = *(const ushort4*)(gp0 + d1);

    for (int k = wave; k < KTOP; k += 8) {
        // issue next gather before touching current data
        const int kn = (k + 8 < KTOP) ? (k + 8) : k;
        const ushort_t* gn = fb + (size_t)kid[kn] * D;
        const bf16x8 ng0 = *(const bf16x8*)(gn + d0);
        const ushort4 ng1 = *(const ushort4*)(gn + d1);

        f32x2 gf[6];
        gf[0] = f32x2{(float)cg0[0], (float)cg0[1]};
        gf[1] = f32x2{(float)cg0[2], (float)cg0[3]};
        gf[2] = f32x2{(float)cg0[4], (float)cg0[5]};
        gf[3] = f32x2{(float)cg0[6], (float)cg0[7]};
        gf[4] = f32x2{bf2f(cg1.x), bf2f(cg1.y)};
        gf[5] = f32x2{bf2f(cg1.z), bf2f(cg1.w)};

        f32x2 s2 = {0.f, 0.f};
#pragma unroll
        for (int jj = 0; jj < 6; ++jj) {
            f32x2 x = gf[jj] + fdr[jj];
            x = __builtin_elementwise_max(x, x * 0.2f);   // leaky(x)
            s2 += x * avr[jj];
        }
        float s = s2.x + s2.y;
#pragma unroll
        for (int off = 32; off > 0; off >>= 1) s += __shfl_xor(s, off);
        s = (kvv[k] > 0.f) ? s : -1e9f;

        // defer-max: rescale only when the max moves by >8 (first iter: rs=0)
        if (s > m_run + 8.f) {
            const float rs = __expf(m_run - s);
            l_run *= rs;
#pragma unroll
            for (int jj = 0; jj < 6; ++jj) acc[jj] *= rs;
            m_run = s;
        }
        const float p = __expf(s - m_run);
        l_run += p;
#pragma unroll
        for (int jj = 0; jj < 6; ++jj) acc[jj] += p * gf[jj];

        cg0 = ng0; cg1 = ng1;
    }

    if (lane == 0) { wm[wave] = m_run; wl[wave] = l_run; }
    *(f32x2*)&hpart[wave][d0]     = acc[0];
    *(f32x2*)&hpart[wave][d0 + 2] = acc[1];
    *(f32x2*)&hpart[wave][d0 + 4] = acc[2];
    *(f32x2*)&hpart[wave][d0 + 6] = acc[3];
    *(f32x2*)&hpart[wave][d1]     = acc[4];
    *(f32x2*)&hpart[wave][d1 + 2] = acc[5];
    __syncthreads();

    // 8-way flash merge + epilogue (d = tid, and d = tid+512 for tid<256)
    float M = wm[0];
#pragma unroll
    for (int w = 1; w < 8; ++w) M = fmaxf(M, wm[w]);
    float rw[8];
    float Lsum = 0.f;
#pragma unroll
    for (int w = 0; w < 8; ++w) { rw[w] = __expf(wm[w] - M); Lsum += rw[w] * wl[w]; }
    const float invL = 1.f / Lsum;

    float dotp = 0.f;
    const float* hid = hidden + (size_t)row * D;
    ushort_t* hb = h + (size_t)row * D;
    {
        const int d = tid;
        float hv = 0.f;
#pragma unroll
        for (int w = 0; w < 8; ++w) hv += rw[w] * hpart[w][d];
        hv *= invL;
        float v = hv + hid[d] + gat_bias[d];
        v = v > 0.f ? v : 0.01f * v;
        hb[d] = f2bf(v);
        dotp += v * gate_W[d];
    }
    if (tid < 256) {
        const int d = tid + 512;
        float hv = 0.f;
#pragma unroll
        for (int w = 0; w < 8; ++w) hv += rw[w] * hpart[w][d];
        hv *= invL;
        float v = hv + hid[d] + gat_bias[d];
        v = v > 0.f ? v : 0.01f * v;
        hb[d] = f2bf(v);
        dotp += v * gate_W[d];
    }
#pragma unroll
    for (int off = 32; off > 0; off >>= 1) dotp += __shfl_xor(dotp, off);
    if (lane == 0) gred[wave] = dotp;
    __syncthreads();
    if (tid == 0) {
        float g = gate_b[0];
#pragma unroll
        for (int w = 0; w < 8; ++w) g += gred[w];
        gate[row] = g;
    }
}

// ---------------------------------------------------------------------------
// pool (gate-softmax fused): per-batch softmax stats over gate via shuffle
// reductions, then accumulate 64-l chunk of pooled[b][d]. h is bf16.
// 96 blocks (R5 lesson: keep grid >= CU-scale; atomics are cheap here).
// ---------------------------------------------------------------------------
__global__ __launch_bounds__(256) void pool_kernel(const ushort_t* __restrict__ h,
                                                   const float* __restrict__ gate,
                                                   float* __restrict__ pooled) {
    const int b = blockIdx.z;
    const int lbase = blockIdx.y * 64;
    const int d = blockIdx.x * 256 + threadIdx.x;
    const int tid = threadIdx.x;
    const int lane = tid & 63;
    const int w = tid >> 6;

    __shared__ float wred[4];
    __shared__ float ps[64];

    const float g0 = gate[b * LSEQ + tid];
    const float g1 = gate[b * LSEQ + tid + 256];
    float m = fmaxf(g0, g1);
#pragma unroll
    for (int off = 32; off > 0; off >>= 1) m = fmaxf(m, __shfl_xor(m, off));
    if (lane == 0) wred[w] = m;
    __syncthreads();
    m = fmaxf(fmaxf(wred[0], wred[1]), fmaxf(wred[2], wred[3]));
    float e = __expf(g0 - m) + __expf(g1 - m);
#pragma unroll
    for (int off = 32; off > 0; off >>= 1) e += __shfl_xor(e, off);
    __syncthreads();
    if (lane == 0) wred[w] = e;
    __syncthreads();
    const float inv = 1.f / (wred[0] + wred[1] + wred[2] + wred[3]);
    if (tid < 64) ps[tid] = __expf(gate[b * LSEQ + lbase + tid] - m) * inv;
    __syncthreads();

    const ushort_t* hb = h + ((size_t)(b * LSEQ + lbase)) * D + d;
    float acc = 0.f;
#pragma unroll 8
    for (int l = 0; l < 64; ++l) {
        acc += ps[l] * bf2f(hb[(size_t)l * D]);
    }
    atomicAdd(&pooled[b * D + d], acc);
}

// ---------------------------------------------------------------------------
// fc (LN1 fused + ln2 last-block fused): relu+LN(768) stats from pooled,
// normalize 256-d chunk into LDS, partial z atomicAdd. The LAST of the 18
// blocks for batch b (device-scope counter) then inline-runs ln2 for b.
// ---------------------------------------------------------------------------
__global__ __launch_bounds__(256) void fc_kernel(const float* __restrict__ pooled,
                                                 const float* __restrict__ ln_g,
                                                 const float* __restrict__ ln_b,
                                                 const float* __restrict__ fc_W,
                                                 float* __restrict__ z,
                                                 int* __restrict__ cnt,
                                                 const float* __restrict__ fc_b,
                                                 const float* __restrict__ ln2_g,
                                                 const float* __restrict__ ln2_b,
                                                 float* __restrict__ out) {
    const int b = blockIdx.z;
    const int by = blockIdx.y;          // 0..2, which 256-d chunk
    const int dbase = by * 256;
    const int jbase = blockIdx.x * 64;
    const int tid = threadIdx.x;
    const int lane = tid & 63;
    const int w = tid >> 6;
    const int jt = tid & 63;
    const int sub = tid >> 6;

    __shared__ float wred[4];
    __shared__ float ys[256];
    __shared__ float part[4][64];
    __shared__ int   amLast;

    float v[3];
#pragma unroll
    for (int i = 0; i < 3; ++i) v[i] = fmaxf(pooled[b * D + tid + i * 256], 0.f);

    float s = v[0] + v[1] + v[2];
#pragma unroll
    for (int off = 32; off > 0; off >>= 1) s += __shfl_xor(s, off);
    if (lane == 0) wred[w] = s;
    __syncthreads();
    const float mu = (wred[0] + wred[1] + wred[2] + wred[3]) / (float)D;
    float vs = 0.f;
#pragma unroll
    for (int i = 0; i < 3; ++i) { const float dd = v[i] - mu; vs += dd * dd; }
#pragma unroll
    for (int off = 32; off > 0; off >>= 1) vs += __shfl_xor(vs, off);
    __syncthreads();                 // protect wred before reuse
    if (lane == 0) wred[w] = vs;
    __syncthreads();
    const float rstd = rsqrtf((wred[0] + wred[1] + wred[2] + wred[3]) / (float)D + EPS);

    const float vb = (by == 0) ? v[0] : (by == 1 ? v[1] : v[2]);
    ys[tid] = (vb - mu) * rstd * ln_g[dbase + tid] + ln_b[dbase + tid];
    __syncthreads();

    const float* W = fc_W + (size_t)(dbase + sub * 64) * DOUT + jbase + jt;
    const float* yy = ys + sub * 64;
    float acc = 0.f;
#pragma unroll 8
    for (int i = 0; i < 64; ++i) {
        acc += yy[i] * W[(size_t)i * DOUT];
    }
    part[sub][jt] = acc;
    __syncthreads();
    if (sub == 0) {
        const float tot = part[0][jt] + part[1][jt] + part[2][jt] + part[3][jt];
        atomicAdd(&z[b * DOUT + jbase + jt], tot);
    }

    // ---- last-block ln2 for this batch ----
    __threadfence();                  // release our z contributions
    __syncthreads();
    if (tid == 0) amLast = (atomicAdd(&cnt[b], 1) == 17);
    __syncthreads();
    if (!amLast) return;
    __threadfence();                  // acquire all 18 blocks' z writes

    const bool has2 = tid < (DOUT - 256);   // tid < 128
    const float v0 = z[b * DOUT + tid] + fc_b[tid];
    const float v1 = has2 ? z[b * DOUT + tid + 256] + fc_b[tid + 256] : 0.f;

    float sm = v0 + v1;
#pragma unroll
    for (int off = 32; off > 0; off >>= 1) sm += __shfl_xor(sm, off);
    __syncthreads();
    if (lane == 0) wred[w] = sm;
    __syncthreads();
    const float mu2 = (wred[0] + wred[1] + wred[2] + wred[3]) / (float)DOUT;

    const float dd0 = v0 - mu2;
    const float dd1 = v1 - mu2;
    float s2 = dd0 * dd0 + (has2 ? dd1 * dd1 : 0.f);
#pragma unroll
    for (int off = 32; off > 0; off >>= 1) s2 += __shfl_xor(s2, off);
    __syncthreads();
    if (lane == 0) wred[w] = s2;
    __syncthreads();
    const float rstd2 = rsqrtf((wred[0] + wred[1] + wred[2] + wred[3]) / (float)DOUT + EPS);

    out[b * DOUT + tid] = dd0 * rstd2 * ln2_g[tid] + ln2_b[tid];
    if (has2)
        out[b * DOUT + tid + 256] = dd1 * rstd2 * ln2_g[tid + 256] + ln2_b[tid + 256];
}

extern "C" void kernel_launch(void* const* d_in, const int* in_sizes, int n_in,
                              void* d_out, int out_size, void* d_ws, size_t ws_size,
                              hipStream_t stream) {
    const float* hidden   = (const float*)d_in[0];   // (4,512,768)
    const float* attention= (const float*)d_in[1];   // (4,512,512)
    const float* W_src    = (const float*)d_in[2];
    const float* b_src    = (const float*)d_in[3];
    const float* W_dst    = (const float*)d_in[4];
    const float* b_dst    = (const float*)d_in[5];
    const float* attn_vec = (const float*)d_in[6];
    const float* gat_bias = (const float*)d_in[7];
    const float* gate_W   = (const float*)d_in[8];
    const float* gate_b   = (const float*)d_in[9];
    const float* ln_g     = (const float*)d_in[10];
    const float* ln_b     = (const float*)d_in[11];
    const float* fc_W     = (const float*)d_in[12];
    const float* fc_b     = (const float*)d_in[13];
    const float* ln2_g    = (const float*)d_in[14];
    const float* ln2_b    = (const float*)d_in[15];
    float* out = (float*)d_out;

    const int M = BATCH * LSEQ;           // 2048
    float* feat_dst = (float*)d_ws;                       // M*D fp32
    float* gate     = feat_dst + (size_t)M * D;           // M
    float* pooled   = gate + M;                           // B*D
    float* z        = pooled + BATCH * D;                 // B*DOUT
    int*   cnt      = (int*)(z + BATCH * DOUT);           // BATCH ints
    float* kvvg     = (float*)(cnt + 64);                 // M*64 fp32 (64 pad)
    int*   kidg     = (int*)(kvvg + (size_t)M * 64);      // M*64 int
    ushort_t* Ah    = (ushort_t*)(kidg + (size_t)M * 64); // M*D bf16
    ushort_t* WT0   = Ah + (size_t)M * D;                 // D*D bf16 [n][k]
    ushort_t* WT1   = WT0 + (size_t)D * D;                // D*D bf16 [n][k]
    ushort_t* fsrcb = WT1 + (size_t)D * D;                // M*D bf16
    ushort_t* h     = fsrcb + (size_t)M * D;              // M*D bf16

    hipLaunchKernelGGL(prep_kernel, dim3(2689 + M), dim3(256), 0, stream,
                       hidden, Ah, W_src, W_dst, WT0, WT1, pooled, z, cnt,
                       attention, kidg, kvvg);
    hipLaunchKernelGGL(feat_gemm_kernel, dim3(768), dim3(256), 0, stream,
                       Ah, WT0, b_src, fsrcb, WT1, b_dst, feat_dst);
    hipLaunchKernelGGL(scoregath_kernel, dim3(M), dim3(512), 0, stream,
                       kidg, kvvg, fsrcb, feat_dst, attn_vec, gat_bias, hidden,
                       gate_W, gate_b, h, gate);
    hipLaunchKernelGGL(pool_kernel, dim3(D / 256, LSEQ / 64, BATCH), dim3(256), 0, stream,
                       h, gate, pooled);
    hipLaunchKernelGGL(fc_kernel, dim3(DOUT / 64, D / 256, BATCH), dim3(256), 0, stream,
                       pooled, ln_g, ln_b, fc_W, z, cnt, fc_b, ln2_g, ln2_b, out);
}

// Round 10
// 147.700 us; speedup vs baseline: 1.0736x; 1.0736x over previous
//
#include <hip/hip_runtime.h>
#include <math.h>

#define D 768
#define DOUT 384
#define LSEQ 512
#define BATCH 4
#define KTOP 51
#define EPS 1e-5f

typedef unsigned short ushort_t;
typedef __bf16 bf16x8 __attribute__((ext_vector_type(8)));
typedef float f32x4 __attribute__((ext_vector_type(4)));
typedef float f32x2 __attribute__((ext_vector_type(2)));

// global->LDS direct DMA, 16B per lane. LDS dest is wave-uniform base + lane*16.
#define GLOAD16(gp, lp)                                                        \
    __builtin_amdgcn_global_load_lds(                                          \
        (const __attribute__((address_space(1))) unsigned int*)(gp),           \
        (__attribute__((address_space(3))) unsigned int*)(lp), 16, 0, 0)

// fp32 -> bf16 round-to-nearest-even (inputs are finite; NaN path not needed)
__device__ __forceinline__ ushort_t f2bf(float f) {
    unsigned int u = __builtin_bit_cast(unsigned int, f);
    u = (u + 0x7FFFu + ((u >> 16) & 1u)) >> 16;
    return (ushort_t)u;
}

__device__ __forceinline__ float bf2f(ushort_t u) {
    unsigned int v = ((unsigned int)u) << 16;
    return __builtin_bit_cast(float, v);
}

// ---------------------------------------------------------------------------
// Prep: blocks [0,1536) convert hidden fp32->bf16; [1536,2688) do the two
// 768x768 W transposes; 2688 zeroes pooled/z; [2689,4737) run per-row top-51
// (depends only on `attention` input -> overlaps with conversion/transpose,
// and removes the serial topk phases + 3 barriers from scoregath).
// ---------------------------------------------------------------------------
__global__ __launch_bounds__(256) void prep_kernel(const float* __restrict__ hidden,
                                                   ushort_t* __restrict__ Ah,
                                                   const float* __restrict__ W0,
                                                   const float* __restrict__ W1,
                                                   ushort_t* __restrict__ WT0,
                                                   ushort_t* __restrict__ WT1,
                                                   float* __restrict__ pooled,
                                                   float* __restrict__ z,
                                                   const float* __restrict__ attn,
                                                   int* __restrict__ kidg,
                                                   float* __restrict__ kvvg) {
    __shared__ float tile[32][33];
    __shared__ float vals[LSEQ];
    __shared__ float cval[320];
    __shared__ int   cidx[320];
    __shared__ int   nhi, outSlot;
    __shared__ int   kid[KTOP];
    __shared__ float kvv[KTOP];

    const int bid = blockIdx.x;
    const int tid = threadIdx.x;
    if (bid < 1536) {
        const int i = (bid * 256 + tid) * 4;
        const float4 v = *(const float4*)(hidden + i);
        ushort4 o;
        o.x = f2bf(v.x); o.y = f2bf(v.y); o.z = f2bf(v.z); o.w = f2bf(v.w);
        *(ushort4*)(Ah + i) = o;
    } else if (bid < 2688) {
        const int t = bid - 1536;
        const int zz = t / 576;
        const int rem = t - zz * 576;
        const int by = rem / 24, bx = rem - by * 24;
        const float* W = zz ? W1 : W0;
        ushort_t* WT = zz ? WT1 : WT0;
        const int kbase = by * 32;
        const int nbase = bx * 32;
        const int r = tid >> 3, c4 = (tid & 7) * 4;

        const float4 v = *(const float4*)(W + (size_t)(kbase + r) * D + nbase + c4);
        tile[r][c4 + 0] = v.x; tile[r][c4 + 1] = v.y;
        tile[r][c4 + 2] = v.z; tile[r][c4 + 3] = v.w;
        __syncthreads();
        ushort4 o;
        o.x = f2bf(tile[c4 + 0][r]); o.y = f2bf(tile[c4 + 1][r]);
        o.z = f2bf(tile[c4 + 2][r]); o.w = f2bf(tile[c4 + 3][r]);
        *(ushort4*)(WT + (size_t)(nbase + r) * D + kbase + c4) = o;
    } else if (bid == 2688) {
        for (int i = tid; i < BATCH * D; i += 256) pooled[i] = 0.f;
        for (int i = tid; i < BATCH * DOUT; i += 256) z[i] = 0.f;
    } else {
        // -------- per-row top-51 --------
        const int row = bid - 2689;
        const int lane = tid & 63;
        if (tid == 0) { nhi = 0; outSlot = 0; }

        const float* a = attn + (size_t)row * LSEQ;
        const float v0 = a[tid];
        const float v1 = a[tid + 256];
        vals[tid] = v0;
        vals[tid + 256] = v1;
        __syncthreads();

        // ballot compaction: one LDS atomic per wave (slot order irrelevant —
        // rank below is computed over the candidate SET)
        {
            const unsigned long long m0 = __ballot(v0 > 0.75f);
            const unsigned long long m1 = __ballot(v1 > 0.75f);
            const int c0 = __popcll(m0);
            const int c1 = __popcll(m1);
            int base = 0;
            if (lane == 0) base = atomicAdd(&nhi, c0 + c1);
            base = __shfl(base, 0);
            const unsigned long long below = (1ull << lane) - 1ull;
            if (v0 > 0.75f) {
                const int s = base + __popcll(m0 & below);
                if (s < 320) { cval[s] = v0; cidx[s] = tid; }
            }
            if (v1 > 0.75f) {
                const int s = base + c0 + __popcll(m1 & below);
                if (s < 320) { cval[s] = v1; cidx[s] = tid + 256; }
            }
        }
        __syncthreads();

        const int n = nhi;
        if (n >= KTOP && n <= 320) {
            // fast path: rank within survivor set == global rank for survivors
            if (tid < n) {
                const float v = cval[tid];
                const int e = cidx[tid];
                int r = 0;
                int j = 0;
                const int n4 = n & ~3;
                for (; j < n4; j += 4) {
                    const float4 u4 = *(const float4*)&cval[j];
                    const int4 e4 = *(const int4*)&cidx[j];
                    r += (u4.x > v) || (u4.x == v && e4.x < e);
                    r += (u4.y > v) || (u4.y == v && e4.y < e);
                    r += (u4.z > v) || (u4.z == v && e4.z < e);
                    r += (u4.w > v) || (u4.w == v && e4.w < e);
                }
                for (; j < n; ++j) {
                    const float u = cval[j];
                    r += (u > v) || (u == v && cidx[j] < e);
                }
                const bool keep = (r < KTOP);
                const unsigned long long mk = __ballot(keep);
                const int cnt = __popcll(mk);
                if (cnt > 0) {
                    const int leader = __ffsll((unsigned long long)mk) - 1;
                    int base = 0;
                    if (lane == leader) base = atomicAdd(&outSlot, cnt);
                    base = __shfl(base, leader);
                    if (keep) {
                        const int s = base + __popcll(mk & ((1ull << lane) - 1ull));
                        kid[s] = e; kvv[s] = v;
                    }
                }
            }
        } else {
            // exact fallback for arbitrary inputs (rare; serial atomics fine)
#pragma unroll
            for (int e0 = 0; e0 < 2; ++e0) {
                const int e = tid + e0 * 256;
                const float v = vals[e];
                int r = 0;
                for (int j = 0; j < LSEQ; ++j) {
                    const float u = vals[j];
                    r += (u > v) || (u == v && j < e);
                }
                if (r < KTOP) {
                    const int s = atomicAdd(&outSlot, 1);
                    kid[s] = e; kvv[s] = v;
                }
            }
        }
        __syncthreads();
        if (tid < KTOP) {
            kidg[(size_t)row * 64 + tid] = kid[tid];
            kvvg[(size_t)row * 64 + tid] = kvv[tid];
        }
    }
}

// ---------------------------------------------------------------------------
// Feature GEMM (bf16 MFMA): A(2048x768) @ W(768x768) + bias.
// 64x64 tiles, BK=64, chunk-XOR swizzle on both sides. Flattened 768-block
// grid with XCD-aware bijective swizzle (768%8==0): each XCD owns 96
// consecutive work-ids (~2 MB working set, fits the XCD's 4 MB L2).
// 768 blocks = exactly 3/CU (R5 lesson: keep quantization).
// zz==0: W_src -> fsrc_bf (bf16). zz==1: W_dst -> feat_dst (fp32).
// ---------------------------------------------------------------------------
__global__ __launch_bounds__(256) void feat_gemm_kernel(const ushort_t* __restrict__ Ah,
                                                        const ushort_t* __restrict__ WT0,
                                                        const float* __restrict__ b0,
                                                        ushort_t* __restrict__ Csrc_bf,
                                                        const ushort_t* __restrict__ WT1,
                                                        const float* __restrict__ b1,
                                                        float* __restrict__ Cdst) {
    const int bid = blockIdx.x;
    const int wid = (bid & 7) * 96 + (bid >> 3);   // bijective XCD swizzle
    const int zz = wid / 384;
    const int rem = wid - zz * 384;
    const int tileY = rem / 12;          // 0..31 (row-block over M)
    const int tileX = rem - tileY * 12;  // 0..11 (col-block over D)

    const ushort_t* WT = zz ? WT1 : WT0;
    const float* bias = zz ? b1 : b0;

    __shared__ ushort_t As[64 * 64];   // 8 KB
    __shared__ ushort_t Bs[64 * 64];   // 8 KB

    const int tid = threadIdx.x;
    const int lane = tid & 63;
    const int wave = tid >> 6;
    const int quad = lane >> 4;
    const int m15 = lane & 15;
    const int qRow = (wave & 1) * 32;
    const int qCol = (wave >> 1) * 32;

    const int rowBase = tileY * 64;
    const int colBase = tileX * 64;

    const int e0 = tid * 8;          // 2048 bf16 per pass
    const int r0 = e0 >> 6;          // 0..31
    const int c0 = e0 & 63;
    const int cc = c0 >> 3;          // 16B chunk 0..7
    const int csw = (cc ^ (r0 & 7)) << 3;   // swizzled source column
    const ushort_t* Abase = Ah + (size_t)rowBase * D;
    const ushort_t* Bbase = WT + (size_t)colBase * D;

    f32x4 acc[2][2] = {};

    for (int kk = 0; kk < D; kk += 64) {
        __syncthreads();
        GLOAD16(Abase + (size_t)r0 * D + kk + csw, &As[e0]);
        GLOAD16(Abase + (size_t)(r0 + 32) * D + kk + csw, &As[e0 + 2048]);
        GLOAD16(Bbase + (size_t)r0 * D + kk + csw, &Bs[e0]);
        GLOAD16(Bbase + (size_t)(r0 + 32) * D + kk + csw, &Bs[e0 + 2048]);
        __syncthreads();

        bf16x8 a[2][2], b[2][2];
#pragma unroll
        for (int i = 0; i < 2; ++i) {
            const int row = qRow + i * 16 + m15;
            const int sw = row & 7;
#pragma unroll
            for (int ks = 0; ks < 2; ++ks)
                a[i][ks] = *(const bf16x8*)&As[row * 64 + ((((ks << 2) + quad) ^ sw) << 3)];
        }
#pragma unroll
        for (int j = 0; j < 2; ++j) {
            const int row = qCol + j * 16 + m15;
            const int sw = row & 7;
#pragma unroll
            for (int ks = 0; ks < 2; ++ks)
                b[j][ks] = *(const bf16x8*)&Bs[row * 64 + ((((ks << 2) + quad) ^ sw) << 3)];
        }
#pragma unroll
        for (int ks = 0; ks < 2; ++ks)
#pragma unroll
            for (int i = 0; i < 2; ++i)
#pragma unroll
                for (int j = 0; j < 2; ++j)
                    acc[i][j] = __builtin_amdgcn_mfma_f32_16x16x32_bf16(a[i][ks], b[j][ks], acc[i][j], 0, 0, 0);
    }

    // C/D layout: col=lane&15, row=quad*4+reg
    if (zz == 0) {
#pragma unroll
        for (int j = 0; j < 2; ++j) {
            const int col = colBase + qCol + j * 16 + m15;
            const float bv = bias[col];
#pragma unroll
            for (int i = 0; i < 2; ++i) {
                ushort_t* Cp = Csrc_bf + (size_t)(rowBase + qRow + i * 16 + quad * 4) * D + col;
#pragma unroll
                for (int r = 0; r < 4; ++r)
                    Cp[(size_t)r * D] = f2bf(acc[i][j][r] + bv);
            }
        }
    } else {
#pragma unroll
        for (int j = 0; j < 2; ++j) {
            const int col = colBase + qCol + j * 16 + m15;
            const float bv = bias[col];
#pragma unroll
            for (int i = 0; i < 2; ++i) {
                float* Cp = Cdst + (size_t)(rowBase + qRow + i * 16 + quad * 4) * D + col;
#pragma unroll
                for (int r = 0; r < 4; ++r)
                    Cp[(size_t)r * D] = acc[i][j][r] + bv;
            }
        }
    }
}

// ---------------------------------------------------------------------------
// Fused score + gather, SINGLE PASS (online softmax, defer-max): topk is
// PRECOMPUTED in prep (kidg/kvvg) -> this kernel is just: stage 51 pairs ->
// one barrier -> pipelined gather loop (packed-f32) -> cross-wave flash
// merge in LDS -> residual + leaky + h(bf16) store + gate dot.
// ---------------------------------------------------------------------------
__global__ __launch_bounds__(256) void scoregath_kernel(const int* __restrict__ kidg,
                                                        const float* __restrict__ kvvg,
                                                        const ushort_t* __restrict__ fsrc_bf,
                                                        const float* __restrict__ feat_dst,
                                                        const float* __restrict__ attn_vec,
                                                        const float* __restrict__ gat_bias,
                                                        const float* __restrict__ hidden,
                                                        const float* __restrict__ gate_W,
                                                        const float* __restrict__ gate_b,
                                                        ushort_t* __restrict__ h,
                                                        float* __restrict__ gate) {
    const int bid = blockIdx.x;
    const int row = (bid & 7) * 256 + (bid >> 3);   // bijective XCD swizzle
    const int b = row >> 9;
    const int tid = threadIdx.x;
    const int lane = tid & 63;
    const int wave = tid >> 6;

    __shared__ int   kid[KTOP];
    __shared__ float kvv[KTOP];
    __shared__ float wm[4], wl[4];
    __shared__ float hpart[4][D];   // 12 KB
    __shared__ float gred[4];

    if (tid < KTOP) {
        kid[tid] = kidg[(size_t)row * 64 + tid];
        kvv[tid] = kvvg[(size_t)row * 64 + tid];
    }

    // balanced per-lane slice: 12 dims = [lane*8, +8) + [512+lane*4, +4),
    // held as 6 packed f32x2 (v_pk_* on CDNA4)
    const int d0 = lane * 8;
    const int d1 = 512 + lane * 4;
    const float* fdp = feat_dst + (size_t)row * D;
    f32x2 fdr[6], avr[6];
    {
        const float4 f0 = *(const float4*)(fdp + d0);
        const float4 f1 = *(const float4*)(fdp + d0 + 4);
        const float4 f2 = *(const float4*)(fdp + d1);
        const float4 a0 = *(const float4*)(attn_vec + d0);
        const float4 a1 = *(const float4*)(attn_vec + d0 + 4);
        const float4 a2 = *(const float4*)(attn_vec + d1);
        fdr[0] = f32x2{f0.x, f0.y}; fdr[1] = f32x2{f0.z, f0.w};
        fdr[2] = f32x2{f1.x, f1.y}; fdr[3] = f32x2{f1.z, f1.w};
        fdr[4] = f32x2{f2.x, f2.y}; fdr[5] = f32x2{f2.z, f2.w};
        avr[0] = f32x2{a0.x, a0.y}; avr[1] = f32x2{a0.z, a0.w};
        avr[2] = f32x2{a1.x, a1.y}; avr[3] = f32x2{a1.z, a1.w};
        avr[4] = f32x2{a2.x, a2.y}; avr[5] = f32x2{a2.z, a2.w};
    }
    __syncthreads();   // kid/kvv staged

    // single pass: score + online accumulate, wave w owns k = w, w+4, ...
    // software pipeline: preload g[k+4] before processing g[k].
    const ushort_t* fb = fsrc_bf + ((size_t)(b << 9)) * D;
    float m_run = -3.0e38f, l_run = 0.f;
    f32x2 acc[6] = {};

    const ushort_t* gp0 = fb + (size_t)kid[wave] * D;
    bf16x8 cg0 = *(const bf16x8*)(gp0 + d0);
    ushort4 cg1 = *(const ushort4*)(gp0 + d1);

    for (int k = wave; k < KTOP; k += 4) {
        // issue next gather before touching current data
        const int kn = (k + 4 < KTOP) ? (k + 4) : k;
        const ushort_t* gn = fb + (size_t)kid[kn] * D;
        const bf16x8 ng0 = *(const bf16x8*)(gn + d0);
        const ushort4 ng1 = *(const ushort4*)(gn + d1);

        f32x2 gf[6];
        gf[0] = f32x2{(float)cg0[0], (float)cg0[1]};
        gf[1] = f32x2{(float)cg0[2], (float)cg0[3]};
        gf[2] = f32x2{(float)cg0[4], (float)cg0[5]};
        gf[3] = f32x2{(float)cg0[6], (float)cg0[7]};
        gf[4] = f32x2{bf2f(cg1.x), bf2f(cg1.y)};
        gf[5] = f32x2{bf2f(cg1.z), bf2f(cg1.w)};

        f32x2 s2 = {0.f, 0.f};
#pragma unroll
        for (int jj = 0; jj < 6; ++jj) {
            f32x2 x = gf[jj] + fdr[jj];
            x = __builtin_elementwise_max(x, x * 0.2f);   // leaky(x)
            s2 += x * avr[jj];
        }
        float s = s2.x + s2.y;
#pragma unroll
        for (int off = 32; off > 0; off >>= 1) s += __shfl_xor(s, off);
        s = (kvv[k] > 0.f) ? s : -1e9f;

        // defer-max: rescale only when the max moves by >8 (first iter: rs=0)
        if (s > m_run + 8.f) {
            const float rs = __expf(m_run - s);
            l_run *= rs;
#pragma unroll
            for (int jj = 0; jj < 6; ++jj) acc[jj] *= rs;
            m_run = s;
        }
        const float p = __expf(s - m_run);
        l_run += p;
#pragma unroll
        for (int jj = 0; jj < 6; ++jj) acc[jj] += p * gf[jj];

        cg0 = ng0; cg1 = ng1;
    }

    if (lane == 0) { wm[wave] = m_run; wl[wave] = l_run; }
    *(f32x2*)&hpart[wave][d0]     = acc[0];
    *(f32x2*)&hpart[wave][d0 + 2] = acc[1];
    *(f32x2*)&hpart[wave][d0 + 4] = acc[2];
    *(f32x2*)&hpart[wave][d0 + 6] = acc[3];
    *(f32x2*)&hpart[wave][d1]     = acc[4];
    *(f32x2*)&hpart[wave][d1 + 2] = acc[5];
    __syncthreads();

    // flash merge of 4 wave partials + epilogue (3 d's per thread, strided)
    const float M = fmaxf(fmaxf(wm[0], wm[1]), fmaxf(wm[2], wm[3]));
    const float r0 = __expf(wm[0] - M), r1 = __expf(wm[1] - M);
    const float r2 = __expf(wm[2] - M), r3 = __expf(wm[3] - M);
    const float invL = 1.f / (r0 * wl[0] + r1 * wl[1] + r2 * wl[2] + r3 * wl[3]);

    float dotp = 0.f;
    const float* hid = hidden + (size_t)row * D;
    ushort_t* hb = h + (size_t)row * D;
#pragma unroll
    for (int j = 0; j < 3; ++j) {
        const int d = tid + j * 256;
        const float hv = (r0 * hpart[0][d] + r1 * hpart[1][d] +
                          r2 * hpart[2][d] + r3 * hpart[3][d]) * invL;
        float v = hv + hid[d] + gat_bias[d];
        v = v > 0.f ? v : 0.01f * v;
        hb[d] = f2bf(v);
        dotp += v * gate_W[d];
    }
#pragma unroll
    for (int off = 32; off > 0; off >>= 1) dotp += __shfl_xor(dotp, off);
    if (lane == 0) gred[wave] = dotp;
    __syncthreads();
    if (tid == 0) gate[row] = gate_b[0] + gred[0] + gred[1] + gred[2] + gred[3];
}

// ---------------------------------------------------------------------------
// pool (gate-softmax fused): per-batch softmax stats over gate via shuffle
// reductions, then accumulate 64-l chunk of pooled[b][d]. h is bf16.
// 96 blocks (R5 lesson: keep grid >= CU-scale; atomics are cheap here).
// ---------------------------------------------------------------------------
__global__ __launch_bounds__(256) void pool_kernel(const ushort_t* __restrict__ h,
                                                   const float* __restrict__ gate,
                                                   float* __restrict__ pooled) {
    const int b = blockIdx.z;
    const int lbase = blockIdx.y * 64;
    const int d = blockIdx.x * 256 + threadIdx.x;
    const int tid = threadIdx.x;
    const int lane = tid & 63;
    const int w = tid >> 6;

    __shared__ float wred[4];
    __shared__ float ps[64];

    const float g0 = gate[b * LSEQ + tid];
    const float g1 = gate[b * LSEQ + tid + 256];
    float m = fmaxf(g0, g1);
#pragma unroll
    for (int off = 32; off > 0; off >>= 1) m = fmaxf(m, __shfl_xor(m, off));
    if (lane == 0) wred[w] = m;
    __syncthreads();
    m = fmaxf(fmaxf(wred[0], wred[1]), fmaxf(wred[2], wred[3]));
    float e = __expf(g0 - m) + __expf(g1 - m);
#pragma unroll
    for (int off = 32; off > 0; off >>= 1) e += __shfl_xor(e, off);
    __syncthreads();
    if (lane == 0) wred[w] = e;
    __syncthreads();
    const float inv = 1.f / (wred[0] + wred[1] + wred[2] + wred[3]);
    if (tid < 64) ps[tid] = __expf(gate[b * LSEQ + lbase + tid] - m) * inv;
    __syncthreads();

    const ushort_t* hb = h + ((size_t)(b * LSEQ + lbase)) * D + d;
    float acc = 0.f;
#pragma unroll 8
    for (int l = 0; l < 64; ++l) {
        acc += ps[l] * bf2f(hb[(size_t)l * D]);
    }
    atomicAdd(&pooled[b * D + d], acc);
}

// ---------------------------------------------------------------------------
// fc (LN1 fused): relu+LN(768) stats from pooled via shuffle reductions,
// normalize 256-d chunk into LDS, partial z[b][j] += sum_d ys[d]*fc_W[d][j].
// 72 blocks.
// ---------------------------------------------------------------------------
__global__ __launch_bounds__(256) void fc_kernel(const float* __restrict__ pooled,
                                                 const float* __restrict__ ln_g,
                                                 const float* __restrict__ ln_b,
                                                 const float* __restrict__ fc_W,
                                                 float* __restrict__ z) {
    const int b = blockIdx.z;
    const int by = blockIdx.y;          // 0..2, which 256-d chunk
    const int dbase = by * 256;
    const int jbase = blockIdx.x * 64;
    const int tid = threadIdx.x;
    const int lane = tid & 63;
    const int w = tid >> 6;
    const int jt = tid & 63;
    const int sub = tid >> 6;

    __shared__ float wred[4];
    __shared__ float ys[256];
    __shared__ float part[4][64];

    float v[3];
#pragma unroll
    for (int i = 0; i < 3; ++i) v[i] = fmaxf(pooled[b * D + tid + i * 256], 0.f);

    float s = v[0] + v[1] + v[2];
#pragma unroll
    for (int off = 32; off > 0; off >>= 1) s += __shfl_xor(s, off);
    if (lane == 0) wred[w] = s;
    __syncthreads();
    const float mu = (wred[0] + wred[1] + wred[2] + wred[3]) / (float)D;
    float vs = 0.f;
#pragma unroll
    for (int i = 0; i < 3; ++i) { const float dd = v[i] - mu; vs += dd * dd; }
#pragma unroll
    for (int off = 32; off > 0; off >>= 1) vs += __shfl_xor(vs, off);
    __syncthreads();                 // protect wred before reuse
    if (lane == 0) wred[w] = vs;
    __syncthreads();
    const float rstd = rsqrtf((wred[0] + wred[1] + wred[2] + wred[3]) / (float)D + EPS);

    const float vb = (by == 0) ? v[0] : (by == 1 ? v[1] : v[2]);
    ys[tid] = (vb - mu) * rstd * ln_g[dbase + tid] + ln_b[dbase + tid];
    __syncthreads();

    const float* W = fc_W + (size_t)(dbase + sub * 64) * DOUT + jbase + jt;
    const float* yy = ys + sub * 64;
    float acc = 0.f;
#pragma unroll 8
    for (int i = 0; i < 64; ++i) {
        acc += yy[i] * W[(size_t)i * DOUT];
    }
    part[sub][jt] = acc;
    __syncthreads();
    if (sub == 0) {
        const float tot = part[0][jt] + part[1][jt] + part[2][jt] + part[3][jt];
        atomicAdd(&z[b * DOUT + jbase + jt], tot);
    }
}

// ---------------------------------------------------------------------------
// ln2: add bias, LayerNorm(384) -> out.  grid B, block 384 (6 waves).
// ---------------------------------------------------------------------------
__global__ __launch_bounds__(384) void ln2_kernel(const float* __restrict__ z,
                                                  const float* __restrict__ fc_b,
                                                  const float* __restrict__ ln2_g,
                                                  const float* __restrict__ ln2_b,
                                                  float* __restrict__ out) {
    const int b = blockIdx.x;
    const int tid = threadIdx.x;
    const int lane = tid & 63;
    const int wave = tid >> 6;
    __shared__ float wred[6];

    const float v = z[b * DOUT + tid] + fc_b[tid];

    float s = v;
#pragma unroll
    for (int off = 32; off > 0; off >>= 1) s += __shfl_xor(s, off);
    if (lane == 0) wred[wave] = s;
    __syncthreads();
    float mu = 0.f;
#pragma unroll
    for (int w = 0; w < 6; ++w) mu += wred[w];
    mu /= (float)DOUT;
    __syncthreads();

    const float dd = v - mu;
    float s2 = dd * dd;
#pragma unroll
    for (int off = 32; off > 0; off >>= 1) s2 += __shfl_xor(s2, off);
    if (lane == 0) wred[wave] = s2;
    __syncthreads();
    float var = 0.f;
#pragma unroll
    for (int w = 0; w < 6; ++w) var += wred[w];
    const float rstd = rsqrtf(var / (float)DOUT + EPS);

    out[b * DOUT + tid] = dd * rstd * ln2_g[tid] + ln2_b[tid];
}

extern "C" void kernel_launch(void* const* d_in, const int* in_sizes, int n_in,
                              void* d_out, int out_size, void* d_ws, size_t ws_size,
                              hipStream_t stream) {
    const float* hidden   = (const float*)d_in[0];   // (4,512,768)
    const float* attention= (const float*)d_in[1];   // (4,512,512)
    const float* W_src    = (const float*)d_in[2];
    const float* b_src    = (const float*)d_in[3];
    const float* W_dst    = (const float*)d_in[4];
    const float* b_dst    = (const float*)d_in[5];
    const float* attn_vec = (const float*)d_in[6];
    const float* gat_bias = (const float*)d_in[7];
    const float* gate_W   = (const float*)d_in[8];
    const float* gate_b   = (const float*)d_in[9];
    const float* ln_g     = (const float*)d_in[10];
    const float* ln_b     = (const float*)d_in[11];
    const float* fc_W     = (const float*)d_in[12];
    const float* fc_b     = (const float*)d_in[13];
    const float* ln2_g    = (const float*)d_in[14];
    const float* ln2_b    = (const float*)d_in[15];
    float* out = (float*)d_out;

    const int M = BATCH * LSEQ;           // 2048
    float* feat_dst = (float*)d_ws;                       // M*D fp32
    float* gate     = feat_dst + (size_t)M * D;           // M
    float* pooled   = gate + M;                           // B*D
    float* z        = pooled + BATCH * D;                 // B*DOUT
    float* kvvg     = z + BATCH * DOUT;                   // M*64 fp32
    int*   kidg     = (int*)(kvvg + (size_t)M * 64);      // M*64 int
    ushort_t* Ah    = (ushort_t*)(kidg + (size_t)M * 64); // M*D bf16
    ushort_t* WT0   = Ah + (size_t)M * D;                 // D*D bf16 [n][k]
    ushort_t* WT1   = WT0 + (size_t)D * D;                // D*D bf16 [n][k]
    ushort_t* fsrcb = WT1 + (size_t)D * D;                // M*D bf16
    ushort_t* h     = fsrcb + (size_t)M * D;              // M*D bf16

    hipLaunchKernelGGL(prep_kernel, dim3(2689 + M), dim3(256), 0, stream,
                       hidden, Ah, W_src, W_dst, WT0, WT1, pooled, z,
                       attention, kidg, kvvg);
    hipLaunchKernelGGL(feat_gemm_kernel, dim3(768), dim3(256), 0, stream,
                       Ah, WT0, b_src, fsrcb, WT1, b_dst, feat_dst);
    hipLaunchKernelGGL(scoregath_kernel, dim3(M), dim3(256), 0, stream,
                       kidg, kvvg, fsrcb, feat_dst, attn_vec, gat_bias, hidden,
                       gate_W, gate_b, h, gate);
    hipLaunchKernelGGL(pool_kernel, dim3(D / 256, LSEQ / 64, BATCH), dim3(256), 0, stream,
                       h, gate, pooled);
    hipLaunchKernelGGL(fc_kernel, dim3(DOUT / 64, D / 256, BATCH), dim3(256), 0, stream,
                       pooled, ln_g, ln_b, fc_W, z);
    hipLaunchKernelGGL(ln2_kernel, dim3(BATCH), dim3(384), 0, stream,
                       z, fc_b, ln2_g, ln2_b, out);
}